// Round 16
// baseline (438.044 us; speedup 1.0000x reference)
//
#include <hip/hip_runtime.h>
#include <math.h>

#define NN 100000
#define EE 1600000
#define HH 128
#define GG 512
#define OUTD 10
#define NB 196   // buckets of 512 nodes: bucket = c >> 9
#define BSH 9
#define CAP 10240  // padded bucket capacity (mean 8192, +22 sigma)

typedef _Float16 f16x2 __attribute__((ext_vector_type(2)));
typedef _Float16 f16x4 __attribute__((ext_vector_type(4)));
typedef _Float16 f16x8 __attribute__((ext_vector_type(8)));
typedef float f32x4 __attribute__((ext_vector_type(4)));

// ---------------- init ----------------
__global__ void init_kernel(int* gs, int* ge, int* bcursor, float* out) {
  int i = blockIdx.x * 256 + threadIdx.x;
  if (i < GG) { gs[i] = 0; ge[i] = 0; }
  if (i < NB) bcursor[i] = i * CAP;
  if (i == 0) out[GG * OUTD] = 0.0f; // the scalar second output
}

// ---------------- pass B: scatter {r,c} into padded bucket regions ----------------
__global__ __launch_bounds__(256) void binB_kernel(const int* __restrict__ ei,
                                                   int* __restrict__ bcursor,
                                                   int2* __restrict__ ebuf) {
  __shared__ int lh[NB];
  __shared__ int lbase[NB];
  for (int i = threadIdx.x; i < NB; i += 256) lh[i] = 0;
  __syncthreads();
  int e0 = blockIdx.x * 2048 + threadIdx.x;
  int r_[8], c_[8], rank_[8];
  int e = e0;
#pragma unroll
  for (int i = 0; i < 8; i++, e += 256) {
    if (e < EE) {
      r_[i] = ei[e];
      c_[i] = ei[EE + e];
      rank_[i] = atomicAdd(&lh[c_[i] >> BSH], 1);
    }
  }
  __syncthreads();
  for (int i = threadIdx.x; i < NB; i += 256)
    lbase[i] = lh[i] ? atomicAdd(&bcursor[i], lh[i]) : 0;
  __syncthreads();
  e = e0;
#pragma unroll
  for (int i = 0; i < 8; i++, e += 256) {
    if (e < EE) {
      int b = c_[i] >> BSH;
      ebuf[lbase[b] + rank_[i]] = make_int2(r_[i], c_[i]);
    }
  }
}

// ---------------- pass D: per-bucket degree count + local prefix -> rng{start,end}, dis ----------------
__global__ __launch_bounds__(256) void binD_kernel(const int2* __restrict__ ebuf,
                                                   const int* __restrict__ bcursor,
                                                   int2* __restrict__ rng,
                                                   float* __restrict__ dis) {
  __shared__ int lcnt[512];
  __shared__ int lsum[256];
  int b = blockIdx.x, t = threadIdx.x;
  for (int i = t; i < 512; i += 256) lcnt[i] = 0;
  __syncthreads();
  int s = b * CAP, e = bcursor[b];
  for (int i = s + t; i < e; i += 256)
    atomicAdd(&lcnt[ebuf[i].y & 511], 1);
  __syncthreads();
  int c0 = lcnt[2 * t], c1 = lcnt[2 * t + 1];
  lsum[t] = c0 + c1;
  __syncthreads();
  for (int off = 1; off < 256; off <<= 1) {
    int x = (t >= off) ? lsum[t - off] : 0;
    __syncthreads();
    lsum[t] += x;
    __syncthreads();
  }
  int excl = (t == 0) ? 0 : lsum[t - 1];
  int base = b << BSH;
  int n0 = base + 2 * t, n1 = base + 2 * t + 1;
  int st0 = s + excl;
  if (n0 < NN) { rng[n0] = make_int2(st0, st0 + c0);       dis[n0] = rsqrtf((float)(c0 + 1)); }
  if (n1 < NN) { rng[n1] = make_int2(st0 + c0, st0 + c0 + c1); dis[n1] = rsqrtf((float)(c1 + 1)); }
}

// ---------------- pass C: per-bucket fine scatter with LDS cursors ----------------
__global__ __launch_bounds__(256) void binC_kernel(const int2* __restrict__ ebuf,
                                                   const int* __restrict__ bcursor,
                                                   const int2* __restrict__ rng,
                                                   const float* __restrict__ dis,
                                                   int2* __restrict__ csr_p) {
  __shared__ int lcur[512];
  int b = blockIdx.x;
  int base = b << BSH;
  for (int i = threadIdx.x; i < 512; i += 256) {
    int node = base + i;
    lcur[i] = (node < NN) ? rng[node].x : 0;
  }
  __syncthreads();
  int s = b * CAP, e = bcursor[b];
  for (int i = s + threadIdx.x; i < e; i += 256) {
    int2 rc = ebuf[i];
    int slot = atomicAdd(&lcur[rc.y & 511], 1);
    csr_p[slot] = make_int2(rc.x, __float_as_int(dis[rc.x]));
  }
}

// ---------------- weight transpose + fp16 convert: Wt[m][c][k] = W_m[k][c] ----------------
__global__ void prep_kernel(const float* __restrict__ W0, const float* __restrict__ W1,
                            const float* __restrict__ W2, const float* __restrict__ gW1,
                            _Float16* __restrict__ Wt) {
  int idx = blockIdx.x * 256 + threadIdx.x;   // 4*128*128 = 65536
  int m = idx >> 14;
  int rem = idx & 16383;
  int c = rem >> 7;
  int k = rem & 127;
  const float* src = (m == 0) ? W0 : (m == 1) ? W1 : (m == 2) ? W2 : gW1;
  Wt[idx] = (_Float16)src[k * 128 + c];
}

// ---------------- MFMA GEMM: [nrows,128] @ [128,128] ----------------
// MODE 0: LDS-staged coalesced f16x8 store. MODE 2: fused gate epilogue.
template <int AF32, int MODE>
__global__ __launch_bounds__(256) void gemm_kernel(const void* __restrict__ Av,
                                                   const _Float16* __restrict__ Wt,
                                                   const float* __restrict__ bias,
                                                   _Float16* __restrict__ out,
                                                   const float* __restrict__ gW2,
                                                   const float* __restrict__ gb2,
                                                   float* __restrict__ gate, int nrows) {
  __shared__ __align__(16) _Float16 wlds[128 * 136];  // padded stride 136 halves (272 B)
  int t = threadIdx.x;
  const uint4* src = (const uint4*)Wt;
#pragma unroll
  for (int i = 0; i < 8; i++) {
    int q = t + 256 * i;
    int c = q >> 4, p = q & 15;
    *(uint4*)&wlds[c * 136 + p * 8] = src[q];
  }
  __syncthreads();

  int wid = t >> 6, l = t & 63;
  int wr0 = blockIdx.x * 64 + wid * 16;
  int row = wr0 + (l & 15);
  bool valid = row < nrows;
  f16x8 zero8 = {(_Float16)0, (_Float16)0, (_Float16)0, (_Float16)0,
                 (_Float16)0, (_Float16)0, (_Float16)0, (_Float16)0};
  f16x8 af[4];
  if (AF32) {
    const float* ap = (const float*)Av + (size_t)row * 128;
#pragma unroll
    for (int kt = 0; kt < 4; kt++) {
      if (valid) {
        const float4* p4 = (const float4*)(ap + kt * 32 + (l >> 4) * 8);
        float4 u0 = p4[0], u1 = p4[1];
        f16x8 a;
        a[0] = (_Float16)u0.x; a[1] = (_Float16)u0.y; a[2] = (_Float16)u0.z; a[3] = (_Float16)u0.w;
        a[4] = (_Float16)u1.x; a[5] = (_Float16)u1.y; a[6] = (_Float16)u1.z; a[7] = (_Float16)u1.w;
        af[kt] = a;
      } else af[kt] = zero8;
    }
  } else {
    const _Float16* ap = (const _Float16*)Av + (size_t)row * 128;
#pragma unroll
    for (int kt = 0; kt < 4; kt++)
      af[kt] = valid ? *(const f16x8*)(ap + kt * 32 + (l >> 4) * 8) : zero8;
  }

  f32x4 acc[8] = {};
  int ko = (l >> 4) * 16;
#pragma unroll
  for (int n = 0; n < 8; n++) {
    int col = n * 16 + (l & 15);
    const char* base = (const char*)wlds + col * 272;
#pragma unroll
    for (int kt = 0; kt < 4; kt++) {
      f16x8 b = *(const f16x8*)(base + kt * 64 + ko);
      acc[n] = __builtin_amdgcn_mfma_f32_16x16x32_f16(af[kt], b, acc[n], 0, 0, 0);
    }
  }

  if (MODE == 0) {
    // stage C in LDS (reuse wlds; 64 rows x 136-stride fp16 = 17.4 KB), then coalesced f16x8 stores
    __syncthreads();
    _Float16* cst = (_Float16*)wlds;
#pragma unroll
    for (int n = 0; n < 8; n++) {
      int col = n * 16 + (l & 15);
#pragma unroll
      for (int r = 0; r < 4; r++) {
        int lrow = wid * 16 + (l >> 4) * 4 + r;   // 0..63
        cst[lrow * 136 + col] = (_Float16)acc[n][r];
      }
    }
    __syncthreads();
    int row0 = blockIdx.x * 64;
    f16x8* o8 = (f16x8*)out;
#pragma unroll
    for (int i = 0; i < 4; i++) {
      int q = t + 256 * i;        // 0..1023 : row = q>>4, chunk = q&15
      int lr = q >> 4;
      int gr = row0 + lr;
      if (gr < nrows)
        o8[(size_t)gr * 16 + (q & 15)] = *(const f16x8*)&cst[lr * 136 + (q & 15) * 8];
    }
  } else {
    float gp[4] = {0.f, 0.f, 0.f, 0.f};
    int c = l & 15;
#pragma unroll
    for (int n = 0; n < 8; n++) {
      int col = n * 16 + c;
      float bv = bias[col];
      float wv = gW2[col];
#pragma unroll
      for (int r = 0; r < 4; r++) gp[r] += fmaxf(acc[n][r] + bv, 0.f) * wv;
    }
#pragma unroll
    for (int m = 1; m < 16; m <<= 1) {
#pragma unroll
      for (int r = 0; r < 4; r++) gp[r] += __shfl_xor(gp[r], m);
    }
    if (c == 0) {
      float gb = gb2[0];
#pragma unroll
      for (int r = 0; r < 4; r++) {
        int orow = wr0 + (l >> 4) * 4 + r;
        if (orow < nrows) gate[orow] = gp[r] + gb;
      }
    }
  }
}

// ---------------- aggregation: wave per node, 2 edges per load (f16x4 halves) ----------------
// out[c] = relu(dc*(sum_e w_e t[src_e] + dc t[c]) + b)   [round-11/13 verified numerics]
__global__ __launch_bounds__(256) void agg_kernel(const _Float16* __restrict__ t,
                                                  const int2* __restrict__ rng,
                                                  const int2* __restrict__ csr_p,
                                                  const float* __restrict__ dis,
                                                  const float* __restrict__ bias,
                                                  _Float16* __restrict__ out) {
  int c = blockIdx.x * 4 + (threadIdx.x >> 6);  // wave per node
  if (c >= NN) return;
  int lane = threadIdx.x & 63;
  int half = lane >> 5;        // 0: even edges, 1: odd edges
  int cl = lane & 31;          // col group: cols 4*cl .. 4*cl+3
  float dc = dis[c];
  int2 rg = rng[c];
  int s = rg.x, e = rg.y;
  const f16x4* t4 = (const f16x4*)t;   // row = 32 f16x4

  float a0 = 0.f, a1 = 0.f, a2 = 0.f, a3 = 0.f;
  if (half == 0) {               // self term in lo half only
    f16x4 hv = t4[(size_t)c * 32 + cl];
    a0 = dc * (float)hv[0]; a1 = dc * (float)hv[1];
    a2 = dc * (float)hv[2]; a3 = dc * (float)hv[3];
  }

  for (int k0 = s; k0 < e; k0 += 64) {
    int cnt = e - k0; if (cnt > 64) cnt = 64;
    int2 pe = csr_p[k0 + (lane < cnt ? lane : cnt - 1)];  // coop stage: lane j holds edge j
    int j = 0;
    for (; j + 16 <= cnt; j += 16) {
      int i0 = j + half,      i1 = j + 2 + half,  i2 = j + 4 + half,  i3 = j + 6 + half;
      int i4 = j + 8 + half,  i5 = j + 10 + half, i6 = j + 12 + half, i7 = j + 14 + half;
      int r0 = __shfl(pe.x, i0), r1 = __shfl(pe.x, i1);
      int r2 = __shfl(pe.x, i2), r3 = __shfl(pe.x, i3);
      int r4 = __shfl(pe.x, i4), r5 = __shfl(pe.x, i5);
      int r6 = __shfl(pe.x, i6), r7 = __shfl(pe.x, i7);
      float w0 = __int_as_float(__shfl(pe.y, i0));
      float w1 = __int_as_float(__shfl(pe.y, i1));
      float w2 = __int_as_float(__shfl(pe.y, i2));
      float w3 = __int_as_float(__shfl(pe.y, i3));
      float w4 = __int_as_float(__shfl(pe.y, i4));
      float w5 = __int_as_float(__shfl(pe.y, i5));
      float w6 = __int_as_float(__shfl(pe.y, i6));
      float w7 = __int_as_float(__shfl(pe.y, i7));
      f16x4 v0 = t4[(size_t)r0 * 32 + cl];
      f16x4 v1 = t4[(size_t)r1 * 32 + cl];
      f16x4 v2 = t4[(size_t)r2 * 32 + cl];
      f16x4 v3 = t4[(size_t)r3 * 32 + cl];
      f16x4 v4 = t4[(size_t)r4 * 32 + cl];
      f16x4 v5 = t4[(size_t)r5 * 32 + cl];
      f16x4 v6 = t4[(size_t)r6 * 32 + cl];
      f16x4 v7 = t4[(size_t)r7 * 32 + cl];
      a0 += w0 * (float)v0[0] + w1 * (float)v1[0] + w2 * (float)v2[0] + w3 * (float)v3[0];
      a1 += w0 * (float)v0[1] + w1 * (float)v1[1] + w2 * (float)v2[1] + w3 * (float)v3[1];
      a2 += w0 * (float)v0[2] + w1 * (float)v1[2] + w2 * (float)v2[2] + w3 * (float)v3[2];
      a3 += w0 * (float)v0[3] + w1 * (float)v1[3] + w2 * (float)v2[3] + w3 * (float)v3[3];
      a0 += w4 * (float)v4[0] + w5 * (float)v5[0] + w6 * (float)v6[0] + w7 * (float)v7[0];
      a1 += w4 * (float)v4[1] + w5 * (float)v5[1] + w6 * (float)v6[1] + w7 * (float)v7[1];
      a2 += w4 * (float)v4[2] + w5 * (float)v5[2] + w6 * (float)v6[2] + w7 * (float)v7[2];
      a3 += w4 * (float)v4[3] + w5 * (float)v5[3] + w6 * (float)v6[3] + w7 * (float)v7[3];
    }
    for (; j + 8 <= cnt; j += 8) {
      int i0 = j + half, i1 = j + 2 + half, i2 = j + 4 + half, i3 = j + 6 + half;
      int r0 = __shfl(pe.x, i0), r1 = __shfl(pe.x, i1);
      int r2 = __shfl(pe.x, i2), r3 = __shfl(pe.x, i3);
      float w0 = __int_as_float(__shfl(pe.y, i0));
      float w1 = __int_as_float(__shfl(pe.y, i1));
      float w2 = __int_as_float(__shfl(pe.y, i2));
      float w3 = __int_as_float(__shfl(pe.y, i3));
      f16x4 v0 = t4[(size_t)r0 * 32 + cl];
      f16x4 v1 = t4[(size_t)r1 * 32 + cl];
      f16x4 v2 = t4[(size_t)r2 * 32 + cl];
      f16x4 v3 = t4[(size_t)r3 * 32 + cl];
      a0 += w0 * (float)v0[0] + w1 * (float)v1[0] + w2 * (float)v2[0] + w3 * (float)v3[0];
      a1 += w0 * (float)v0[1] + w1 * (float)v1[1] + w2 * (float)v2[1] + w3 * (float)v3[1];
      a2 += w0 * (float)v0[2] + w1 * (float)v1[2] + w2 * (float)v2[2] + w3 * (float)v3[2];
      a3 += w0 * (float)v0[3] + w1 * (float)v1[3] + w2 * (float)v2[3] + w3 * (float)v3[3];
    }
    for (; j < cnt; j += 2) {
      int js = j + half;
      bool act = js < cnt;
      int jc = act ? js : cnt - 1;
      int r = __shfl(pe.x, jc);
      float w = act ? __int_as_float(__shfl(pe.y, jc)) : 0.f;
      f16x4 v = t4[(size_t)r * 32 + cl];
      a0 += w * (float)v[0]; a1 += w * (float)v[1];
      a2 += w * (float)v[2]; a3 += w * (float)v[3];
    }
  }

  a0 += __shfl_xor(a0, 32); a1 += __shfl_xor(a1, 32);
  a2 += __shfl_xor(a2, 32); a3 += __shfl_xor(a3, 32);

  if (half == 0) {
    const float4 bv = *(const float4*)&bias[4 * cl];
    f16x4 o;
    o[0] = (_Float16)fmaxf(a0 * dc + bv.x, 0.f);
    o[1] = (_Float16)fmaxf(a1 * dc + bv.y, 0.f);
    o[2] = (_Float16)fmaxf(a2 * dc + bv.z, 0.f);
    o[3] = (_Float16)fmaxf(a3 * dc + bv.w, 0.f);
    ((f16x4*)out)[(size_t)c * 32 + cl] = o;
  }
}

// ---------------- graph boundaries (batch sorted) ----------------
__global__ void bounds_kernel(const int* __restrict__ batch, int* gs, int* ge) {
  int i = blockIdx.x * 256 + threadIdx.x;
  if (i >= NN) return;
  int b = batch[i];
  if (i == 0 || batch[i - 1] != b) gs[b] = i;
  if (i == NN - 1 || batch[i + 1] != b) ge[b] = i + 1;
}

// ---------------- per-graph softmax + pool + MLP head ----------------
__global__ __launch_bounds__(256) void poolhead_kernel(
    const _Float16* __restrict__ h, const float* __restrict__ gate,
    const int* __restrict__ gs, const int* __restrict__ ge,
    const float* __restrict__ lW1, const float* __restrict__ lb1,
    const float* __restrict__ lW2, const float* __restrict__ lb2,
    float* __restrict__ out) {
  int g = blockIdx.x;
  int t = threadIdx.x;
  int s = gs[g], e = ge[g];
  __shared__ float red[4];
  __shared__ float pax[4][64], pay[4][64];
  __shared__ float pooled[128];
  __shared__ float hid[128];
  int wid = t >> 6, lane = t & 63;

  float m = -3.0e38f;
  for (int i = s + t; i < e; i += 256) m = fmaxf(m, gate[i]);
#pragma unroll
  for (int o = 32; o > 0; o >>= 1) m = fmaxf(m, __shfl_xor(m, o));
  if (lane == 0) red[wid] = m;
  __syncthreads();
  m = fmaxf(fmaxf(red[0], red[1]), fmaxf(red[2], red[3]));
  __syncthreads();

  float ds_ = 0.f;
  for (int i = s + t; i < e; i += 256) ds_ += __expf(gate[i] - m);
#pragma unroll
  for (int o = 32; o > 0; o >>= 1) ds_ += __shfl_xor(ds_, o);
  if (lane == 0) red[wid] = ds_;
  __syncthreads();
  float denom = red[0] + red[1] + red[2] + red[3];

  const f16x2* h2 = (const f16x2*)h;
  int cp = t & 63, q = t >> 6;
  float px = 0.f, py = 0.f;
  for (int i = s + q; i < e; i += 4) {
    float w = __expf(gate[i] - m);
    f16x2 v = h2[(size_t)i * 64 + cp];
    px += w * (float)v[0];
    py += w * (float)v[1];
  }
  pax[q][cp] = px; pay[q][cp] = py;
  __syncthreads();
  if (t < 64) {
    float inv = (e > s) ? 1.f / denom : 0.f;
    float sx = pax[0][t] + pax[1][t] + pax[2][t] + pax[3][t];
    float sy = pay[0][t] + pay[1][t] + pay[2][t] + pay[3][t];
    pooled[2 * t] = sx * inv;
    pooled[2 * t + 1] = sy * inv;
  }
  __syncthreads();

  if (t < 128) {
    float hv = lb1[t];
    for (int k = 0; k < 128; k++) hv += pooled[k] * lW1[k * 128 + t];
    hid[t] = fmaxf(hv, 0.f);
  }
  __syncthreads();

  if (t < OUTD) {
    float acc2 = lb2[t];
    for (int k = 0; k < 128; k++) acc2 += hid[k] * lW2[k * OUTD + t];
    out[g * OUTD + t] = acc2;
  }
}

extern "C" void kernel_launch(void* const* d_in, const int* in_sizes, int n_in,
                              void* d_out, int out_size, void* d_ws, size_t ws_size,
                              hipStream_t stream) {
  const float* x   = (const float*)d_in[0];
  const int*   ei  = (const int*)d_in[1];
  const int* batch = (const int*)d_in[2];
  const float* W0  = (const float*)d_in[3];
  const float* b0  = (const float*)d_in[4];
  const float* W1  = (const float*)d_in[5];
  const float* b1  = (const float*)d_in[6];
  const float* W2  = (const float*)d_in[7];
  const float* b2  = (const float*)d_in[8];
  const float* gW1 = (const float*)d_in[9];
  const float* gb1 = (const float*)d_in[10];
  const float* gW2 = (const float*)d_in[11];
  const float* gb2 = (const float*)d_in[12];
  const float* lW1 = (const float*)d_in[13];
  const float* lb1 = (const float*)d_in[14];
  const float* lW2 = (const float*)d_in[15];
  const float* lb2 = (const float*)d_in[16];
  float* out = (float*)d_out;

  char* w = (char*)d_ws;
  auto alloc = [&](size_t bytes) {
    char* p = w;
    w += (bytes + 255) & ~(size_t)255;
    return p;
  };
  _Float16* T  = (_Float16*)alloc((size_t)NN * 128 * 2);
  _Float16* HA = (_Float16*)alloc((size_t)NN * 128 * 2);
  _Float16* HB = (_Float16*)alloc((size_t)NN * 128 * 2);
  _Float16* Wt = (_Float16*)alloc((size_t)4 * 128 * 128 * 2);
  int2* rng    = (int2*)alloc((size_t)NN * 8);
  float* dis   = (float*)alloc((size_t)NN * 4);
  int2* csr_p  = (int2*)alloc((size_t)NB * CAP * 8);
  int2* ebuf   = (int2*)alloc((size_t)NB * CAP * 8);
  float* gate  = (float*)alloc((size_t)NN * 4);
  int* gs      = (int*)alloc(GG * 4);
  int* ge      = (int*)alloc(GG * 4);
  int* bcursor = (int*)alloc(NB * 4);

  dim3 b256(256);
  init_kernel<<<dim3(2), b256, 0, stream>>>(gs, ge, bcursor, out);
  prep_kernel<<<dim3(256), b256, 0, stream>>>(W0, W1, W2, gW1, Wt);
  binB_kernel<<<dim3((EE + 2047) / 2048), b256, 0, stream>>>(ei, bcursor, ebuf);
  binD_kernel<<<dim3(NB), b256, 0, stream>>>(ebuf, bcursor, rng, dis);
  binC_kernel<<<dim3(NB), b256, 0, stream>>>(ebuf, bcursor, rng, dis, csr_p);

  int gblocks = (NN + 63) / 64;
  int ablocks = (NN + 3) / 4;
  // layer 0 (A = x in f32)
  gemm_kernel<1, 0><<<dim3(gblocks), b256, 0, stream>>>(x, Wt + 0 * 16384, nullptr, T, nullptr, nullptr, nullptr, NN);
  agg_kernel<<<dim3(ablocks), b256, 0, stream>>>(T, rng, csr_p, dis, b0, HA);
  // layer 1
  gemm_kernel<0, 0><<<dim3(gblocks), b256, 0, stream>>>(HA, Wt + 1 * 16384, nullptr, T, nullptr, nullptr, nullptr, NN);
  agg_kernel<<<dim3(ablocks), b256, 0, stream>>>(T, rng, csr_p, dis, b1, HB);
  // layer 2
  gemm_kernel<0, 0><<<dim3(gblocks), b256, 0, stream>>>(HB, Wt + 2 * 16384, nullptr, T, nullptr, nullptr, nullptr, NN);
  agg_kernel<<<dim3(ablocks), b256, 0, stream>>>(T, rng, csr_p, dis, b2, HA);

  // gate network: gate = relu(HA@gW1+gb1) . gW2 + gb2  (fused epilogue, no T store)
  gemm_kernel<0, 2><<<dim3(gblocks), b256, 0, stream>>>(HA, Wt + 3 * 16384, gb1, nullptr, gW2, gb2, gate, NN);
  bounds_kernel<<<dim3((NN + 255) / 256), b256, 0, stream>>>(batch, gs, ge);
  poolhead_kernel<<<dim3(GG), b256, 0, stream>>>(HA, gate, gs, ge, lW1, lb1, lW2, lb2, out);
}